// Round 5
// baseline (718.329 us; speedup 1.0000x reference)
//
#include <hip/hip_runtime.h>

#define D 256
#define GBM 256          // gemm rows per block (16 waves x 16)
#define WT_PITCH 264     // bf16 elements per LDS row (256 + 8 pad)
#define BSH 8            // bucket shift: 256 rows per bucket
#define RPB 256          // rows per bucket
#define NBMAX 512        // max buckets supported
#define TILE 4096        // edges per partition block
#define CTSH 12          // col-tile shift: 4096 S-rows = 2 MB bf16 per tile
#define NKEY (RPB * 32)  // sort keys per bucket: localrow * 32 | coltile

using bf16x8 = __attribute__((ext_vector_type(8))) short;
using f32x4  = __attribute__((ext_vector_type(4))) float;

static __device__ __forceinline__ unsigned short f2bf(float f) {
    unsigned u = __builtin_bit_cast(unsigned, f);
    return (unsigned short)((u + 0x7fffu + ((u >> 16) & 1u)) >> 16);  // RNE
}
static __device__ __forceinline__ float as_f(unsigned u) {
    return __builtin_bit_cast(float, u);
}

// ---------------- W transpose + bf16 cast: Wt[n][k] = bf16(W[k][n]) ----------------
__global__ void wt_kernel(const float* __restrict__ W, unsigned short* __restrict__ Wt) {
    int idx = blockIdx.x * blockDim.x + threadIdx.x;
    int n = idx & 255, k = idx >> 8;
    Wt[n * 256 + k] = f2bf(W[k * 256 + n]);
}

// ---------------- GEMM: S(bf16) = X @ W via MFMA, full Wt in LDS ----------------
__global__ __launch_bounds__(1024) void gemm_mfma(const float* __restrict__ X,
                                                  const unsigned short* __restrict__ Wt,
                                                  unsigned short* __restrict__ S, int N) {
    __shared__ unsigned short wlds[256 * WT_PITCH];    // 132 KB

    for (int c = threadIdx.x; c < 8192; c += 1024) {
        int n = c >> 5, kc = c & 31;
        uint4 v = *reinterpret_cast<const uint4*>(Wt + n * 256 + kc * 8);
        *reinterpret_cast<uint4*>(&wlds[n * WT_PITCH + kc * 8]) = v;
    }
    __syncthreads();

    const int lane = threadIdx.x & 63;
    const int wave = threadIdx.x >> 6;
    const int row0 = blockIdx.x * GBM + wave * 16;
    const int l16  = lane & 15;
    const int kgrp = lane >> 4;
    const int arow = min(row0 + l16, N - 1);
    const float* xp = X + (size_t)arow * 256 + kgrp * 8;

    f32x4 acc[16];
#pragma unroll
    for (int i = 0; i < 16; i++) acc[i] = (f32x4)(0.0f);

#pragma unroll
    for (int ks = 0; ks < 8; ks++) {
        float4 a0 = *reinterpret_cast<const float4*>(xp + ks * 32);
        float4 a1 = *reinterpret_cast<const float4*>(xp + ks * 32 + 4);
        bf16x8 af;
        af[0] = (short)f2bf(a0.x); af[1] = (short)f2bf(a0.y);
        af[2] = (short)f2bf(a0.z); af[3] = (short)f2bf(a0.w);
        af[4] = (short)f2bf(a1.x); af[5] = (short)f2bf(a1.y);
        af[6] = (short)f2bf(a1.z); af[7] = (short)f2bf(a1.w);
#pragma unroll
        for (int nt = 0; nt < 16; nt++) {
            bf16x8 bf = *reinterpret_cast<const bf16x8*>(
                &wlds[(nt * 16 + l16) * WT_PITCH + ks * 32 + kgrp * 8]);
            acc[nt] = __builtin_amdgcn_mfma_f32_16x16x32_bf16(af, bf, acc[nt], 0, 0, 0);
        }
    }

#pragma unroll
    for (int nt = 0; nt < 16; nt++) {
#pragma unroll
        for (int j = 0; j < 4; j++) {
            int r = row0 + kgrp * 4 + j;
            if (r < N) S[(size_t)r * 256 + nt * 16 + l16] = f2bf(acc[nt][j]);
        }
    }
}

// ---------------- bucket histogram (LDS-aggregated) ----------------
__global__ __launch_bounds__(256) void bucket_hist(const int* __restrict__ rows,
                                                   int* __restrict__ bcounts,
                                                   int E, int NB) {
    __shared__ int lh[NBMAX];
    for (int i = threadIdx.x; i < NB; i += 256) lh[i] = 0;
    __syncthreads();
    const int stride = gridDim.x * 256;
    for (int e = blockIdx.x * 256 + threadIdx.x; e < E; e += stride)
        atomicAdd(&lh[rows[e] >> BSH], 1);
    __syncthreads();
    for (int i = threadIdx.x; i < NB; i += 256) {
        int v = lh[i];
        if (v) atomicAdd(&bcounts[i], v);
    }
}

// ---------------- bucket scan (NB <= 1024, single block) ----------------
__global__ __launch_bounds__(1024) void bscan_kernel(const int* __restrict__ bcounts,
                                                     int* __restrict__ boffs,
                                                     int* __restrict__ bcursor, int NB) {
    __shared__ int wsum[16];
    const int t = threadIdx.x, lane = t & 63, w = t >> 6;
    int x = (t < NB) ? bcounts[t] : 0;
    int s = x;
#pragma unroll
    for (int d = 1; d < 64; d <<= 1) {
        int y = __shfl_up(s, d);
        if (lane >= d) s += y;
    }
    if (lane == 63) wsum[w] = s;
    __syncthreads();
    if (w == 0) {
        int ws = (lane < 16) ? wsum[lane] : 0;
#pragma unroll
        for (int d = 1; d < 16; d <<= 1) {
            int y = __shfl_up(ws, d);
            if (lane >= d) ws += y;
        }
        if (lane < 16) wsum[lane] = ws;
    }
    __syncthreads();
    int excl = (w ? wsum[w - 1] : 0) + s - x;
    if (t < NB) { boffs[t] = excl; bcursor[t] = excl; }
}

// ---------------- partition: per-block bulk reservation, rank in LDS ----------------
__global__ __launch_bounds__(256) void partition_kernel(const int* __restrict__ rows,
                                                        const int* __restrict__ cols,
                                                        const float* __restrict__ vals,
                                                        int* __restrict__ bcursor,
                                                        int2* __restrict__ packed,
                                                        int E, int NB) {
    __shared__ int lh[NBMAX];
    __shared__ int gbase[NBMAX];
    const int t = threadIdx.x;
    const int e0 = blockIdx.x * TILE;

    for (int i = t; i < NB; i += 256) lh[i] = 0;
    __syncthreads();

    int bk[16], rk[16], pc[16], pv[16];
#pragma unroll
    for (int j = 0; j < 16; j++) {
        int idx = e0 + j * 256 + t;
        if (idx < E) {
            int r = rows[idx];
            bk[j] = r >> BSH;
            rk[j] = atomicAdd(&lh[bk[j]], 1);
            pc[j] = ((r & (RPB - 1)) << 17) | cols[idx];
            pv[j] = __float_as_int(vals[idx]);
        } else {
            bk[j] = -1;
        }
    }
    __syncthreads();

    for (int i = t; i < NB; i += 256) {
        int c = lh[i];
        gbase[i] = c ? atomicAdd(&bcursor[i], c) : 0;
    }
    __syncthreads();

#pragma unroll
    for (int j = 0; j < 16; j++) {
        if (bk[j] >= 0) {
            int2 p; p.x = pc[j]; p.y = pv[j];
            packed[(size_t)gbase[bk[j]] + rk[j]] = p;
        }
    }
}

// ------- per-bucket counting sort by (localrow, coltile) -> CSR (+offs/counts) -------
__global__ __launch_bounds__(256) void bucket_scatter(const int2* __restrict__ packed,
                                                      const int* __restrict__ boffs,
                                                      const int* __restrict__ bcounts,
                                                      int* __restrict__ offs,
                                                      int* __restrict__ counts,
                                                      int2* __restrict__ cv, int N) {
    __shared__ int cnt[NKEY];          // 32 KB: counters -> excl prefix -> cursor
    __shared__ int wsum[4];
    const int b = blockIdx.x, t = threadIdx.x;
    const int base = boffs[b], nb = bcounts[b];
    const int lane = t & 63, w = t >> 6;

    for (int i = t; i < NKEY; i += 256) cnt[i] = 0;
    __syncthreads();
    for (int i = t; i < nb; i += 256) {
        int px = packed[base + i].x;
        int key = ((((unsigned)px) >> 17) << 5) | ((px & 0x1FFFF) >> CTSH);
        atomicAdd(&cnt[key], 1);
    }
    __syncthreads();

    // in-place exclusive scan over NKEY counters (32/thread)
    const int K = NKEY / 256;          // 32
    int tsum = 0;
#pragma unroll
    for (int k = 0; k < K; k++) tsum += cnt[t * K + k];
    int ss = tsum;
#pragma unroll
    for (int d = 1; d < 64; d <<= 1) {
        int y = __shfl_up(ss, d);
        if (lane >= d) ss += y;
    }
    if (lane == 63) wsum[w] = ss;
    __syncthreads();
    int wex = 0;
    if (w > 0) wex += wsum[0];
    if (w > 1) wex += wsum[1];
    if (w > 2) wex += wsum[2];
    int run = wex + ss - tsum;         // exclusive prefix of this thread's chunk
    __syncthreads();                   // all reads of cnt done before overwrite
#pragma unroll
    for (int k = 0; k < K; k++) {
        int c = cnt[t * K + k];
        cnt[t * K + k] = run;
        run += c;
    }
    __syncthreads();

    // emit CSR offs/counts (row group = 32 consecutive keys)
    const int r0 = b << BSH;
    for (int lr = t; lr < RPB; lr += 256) {
        int r = r0 + lr;
        if (r < N) {
            int s0 = cnt[lr << 5];
            int s1 = (lr == RPB - 1) ? nb : cnt[(lr + 1) << 5];
            offs[r] = base + s0;
            counts[r] = s1 - s0;
        }
    }
    __syncthreads();

    // scatter using cnt as cursor
    for (int i = t; i < nb; i += 256) {
        int2 p = packed[base + i];
        int key = ((((unsigned)p.x) >> 17) << 5) | ((p.x & 0x1FFFF) >> CTSH);
        int pos = base + atomicAdd(&cnt[key], 1);
        int2 o;
        o.x = p.x & 0x1FFFF;
        o.y = p.y;
        cv[pos] = o;
    }
}

// ------- SpMM: wave per 16 rows, col-tile sweep (phase-aligned L2 reuse) -------
__global__ __launch_bounds__(256) void spmm_kernel(const unsigned short* __restrict__ S,
                                                   const int* __restrict__ offs,
                                                   const int* __restrict__ counts,
                                                   const int2* __restrict__ cv,
                                                   const float* __restrict__ bias,
                                                   float* __restrict__ out,
                                                   int N, int nct) {
    const int lane = threadIdx.x & 63;
    const int wave = __builtin_amdgcn_readfirstlane(threadIdx.x >> 6);
    const int r0 = blockIdx.x * 64 + wave * 16;
    const char* Sb = reinterpret_cast<const char*>(S);

    float4 acc[16];
    int ip[16], ep[16];
#pragma unroll
    for (int g = 0; g < 16; g++) {
        acc[g] = make_float4(0.f, 0.f, 0.f, 0.f);
        int r = r0 + g;
        if (r < N) { ip[g] = offs[r]; ep[g] = ip[g] + counts[r]; }
        else       { ip[g] = 0; ep[g] = 0; }
    }

#define GATHER(c, v, A)                                                           \
    {                                                                             \
        uint2 sv = *reinterpret_cast<const uint2*>(Sb + ((size_t)(c) << 9) + (lane << 3)); \
        A.x += (v) * as_f(sv.x << 16);                                            \
        A.y += (v) * as_f(sv.x & 0xffff0000u);                                    \
        A.z += (v) * as_f(sv.y << 16);                                            \
        A.w += (v) * as_f(sv.y & 0xffff0000u);                                    \
    }

    for (int ct = 0; ct < nct; ct++) {
        const int bound = (ct + 1) << CTSH;
#pragma unroll
        for (int g = 0; g < 16; g++) {
            int i = ip[g];
            const int e = ep[g];
            while (i < e) {
                int2 p = cv[i];
                if (p.x >= bound) break;
                GATHER(p.x, as_f((unsigned)p.y), acc[g]);
                i++;
            }
            ip[g] = i;
        }
    }
#undef GATHER

    float4 b = reinterpret_cast<const float4*>(bias)[lane];
#pragma unroll
    for (int g = 0; g < 16; g++) {
        int r = r0 + g;
        if (r < N) {
            float4 o = { acc[g].x + b.x, acc[g].y + b.y, acc[g].z + b.z, acc[g].w + b.w };
            reinterpret_cast<float4*>(out)[(size_t)r * 64 + lane] = o;
        }
    }
}

extern "C" void kernel_launch(void* const* d_in, const int* in_sizes, int n_in,
                              void* d_out, int out_size, void* d_ws, size_t ws_size,
                              hipStream_t stream) {
    const float* X     = (const float*)d_in[0];
    const float* W     = (const float*)d_in[1];
    const float* bias  = (const float*)d_in[2];
    const float* evals = (const float*)d_in[3];
    const int*   erow  = (const int*)d_in[4];
    const int*   ecol  = (const int*)d_in[5];
    float* out = (float*)d_out;

    const int N = in_sizes[0] / D;
    const int E = in_sizes[3];
    const int NB = (N + RPB - 1) >> BSH;
    const int nct = ((N - 1) >> CTSH) + 1;

    char* ws = (char*)d_ws;
    size_t off = 0;
    auto alloc = [&](size_t bytes) {
        void* p = ws + off;
        off += (bytes + 255) & ~(size_t)255;
        return p;
    };
    unsigned short* S  = (unsigned short*)alloc((size_t)N * D * sizeof(unsigned short));
    unsigned short* Wt = (unsigned short*)alloc((size_t)D * D * sizeof(unsigned short));
    int* bcounts = (int*)alloc((size_t)NB * sizeof(int));
    int* boffs   = (int*)alloc((size_t)NB * sizeof(int));
    int* bcursor = (int*)alloc((size_t)NB * sizeof(int));
    int* offs    = (int*)alloc((size_t)N * sizeof(int));
    int* counts  = (int*)alloc((size_t)N * sizeof(int));
    int2* packed = (int2*)alloc((size_t)E * sizeof(int2));
    int2* cv     = (int2*)alloc((size_t)E * sizeof(int2));

    // 1. Wt = bf16(W^T)
    wt_kernel<<<(D * D) / 256, 256, 0, stream>>>(W, Wt);
    // 2. S = bf16(X @ W) via MFMA
    gemm_mfma<<<(N + GBM - 1) / GBM, 1024, 0, stream>>>(X, Wt, S, N);
    // 3. two-phase CSR build, sorted by (row, coltile)
    hipMemsetAsync(bcounts, 0, (size_t)NB * sizeof(int), stream);
    bucket_hist<<<1024, 256, 0, stream>>>(erow, bcounts, E, NB);
    bscan_kernel<<<1, 1024, 0, stream>>>(bcounts, boffs, bcursor, NB);
    partition_kernel<<<(E + TILE - 1) / TILE, 256, 0, stream>>>(erow, ecol, evals, bcursor,
                                                                packed, E, NB);
    bucket_scatter<<<NB, 256, 0, stream>>>(packed, boffs, bcounts, offs, counts, cv, N);
    // 4. SpMM + bias (col-tile swept)
    spmm_kernel<<<(N + 63) / 64, 256, 0, stream>>>(S, offs, counts, cv, bias, out, N, nct);
}

// Round 6
// 405.071 us; speedup vs baseline: 1.7733x; 1.7733x over previous
//
#include <hip/hip_runtime.h>

#define D 256
#define GBM 256          // gemm rows per block (16 waves x 16)
#define WT_PITCH 264     // bf16 elements per LDS row (256 + 8 pad)
#define BSH 8            // bucket shift: 256 rows per bucket
#define RPB 256          // rows per bucket
#define NBMAX 512        // max buckets supported
#define TILE 4096        // edges per partition block
#define CTSH 12          // col-tile shift: 4096 S-rows = 2 MB bf16 per tile
#define NKEY (RPB * 32)  // sort keys per bucket: localrow * 32 | coltile

using bf16x8 = __attribute__((ext_vector_type(8))) short;
using f32x4  = __attribute__((ext_vector_type(4))) float;

static __device__ __forceinline__ unsigned short f2bf(float f) {
    unsigned u = __builtin_bit_cast(unsigned, f);
    return (unsigned short)((u + 0x7fffu + ((u >> 16) & 1u)) >> 16);  // RNE
}
static __device__ __forceinline__ float as_f(unsigned u) {
    return __builtin_bit_cast(float, u);
}

// ---------------- W transpose + bf16 cast: Wt[n][k] = bf16(W[k][n]) ----------------
__global__ void wt_kernel(const float* __restrict__ W, unsigned short* __restrict__ Wt) {
    int idx = blockIdx.x * blockDim.x + threadIdx.x;
    int n = idx & 255, k = idx >> 8;
    Wt[n * 256 + k] = f2bf(W[k * 256 + n]);
}

// ---------------- GEMM: S(bf16) = X @ W via MFMA, full Wt in LDS ----------------
__global__ __launch_bounds__(1024) void gemm_mfma(const float* __restrict__ X,
                                                  const unsigned short* __restrict__ Wt,
                                                  unsigned short* __restrict__ S, int N) {
    __shared__ unsigned short wlds[256 * WT_PITCH];    // 132 KB

    for (int c = threadIdx.x; c < 8192; c += 1024) {
        int n = c >> 5, kc = c & 31;
        uint4 v = *reinterpret_cast<const uint4*>(Wt + n * 256 + kc * 8);
        *reinterpret_cast<uint4*>(&wlds[n * WT_PITCH + kc * 8]) = v;
    }
    __syncthreads();

    const int lane = threadIdx.x & 63;
    const int wave = threadIdx.x >> 6;
    const int row0 = blockIdx.x * GBM + wave * 16;
    const int l16  = lane & 15;
    const int kgrp = lane >> 4;
    const int arow = min(row0 + l16, N - 1);
    const float* xp = X + (size_t)arow * 256 + kgrp * 8;

    f32x4 acc[16];
#pragma unroll
    for (int i = 0; i < 16; i++) acc[i] = (f32x4)(0.0f);

#pragma unroll
    for (int ks = 0; ks < 8; ks++) {
        float4 a0 = *reinterpret_cast<const float4*>(xp + ks * 32);
        float4 a1 = *reinterpret_cast<const float4*>(xp + ks * 32 + 4);
        bf16x8 af;
        af[0] = (short)f2bf(a0.x); af[1] = (short)f2bf(a0.y);
        af[2] = (short)f2bf(a0.z); af[3] = (short)f2bf(a0.w);
        af[4] = (short)f2bf(a1.x); af[5] = (short)f2bf(a1.y);
        af[6] = (short)f2bf(a1.z); af[7] = (short)f2bf(a1.w);
#pragma unroll
        for (int nt = 0; nt < 16; nt++) {
            bf16x8 bf = *reinterpret_cast<const bf16x8*>(
                &wlds[(nt * 16 + l16) * WT_PITCH + ks * 32 + kgrp * 8]);
            acc[nt] = __builtin_amdgcn_mfma_f32_16x16x32_bf16(af, bf, acc[nt], 0, 0, 0);
        }
    }

#pragma unroll
    for (int nt = 0; nt < 16; nt++) {
#pragma unroll
        for (int j = 0; j < 4; j++) {
            int r = row0 + kgrp * 4 + j;
            if (r < N) S[(size_t)r * 256 + nt * 16 + l16] = f2bf(acc[nt][j]);
        }
    }
}

// ---------------- bucket histogram (LDS-aggregated) ----------------
__global__ __launch_bounds__(256) void bucket_hist(const int* __restrict__ rows,
                                                   int* __restrict__ bcounts,
                                                   int E, int NB) {
    __shared__ int lh[NBMAX];
    for (int i = threadIdx.x; i < NB; i += 256) lh[i] = 0;
    __syncthreads();
    const int stride = gridDim.x * 256;
    for (int e = blockIdx.x * 256 + threadIdx.x; e < E; e += stride)
        atomicAdd(&lh[rows[e] >> BSH], 1);
    __syncthreads();
    for (int i = threadIdx.x; i < NB; i += 256) {
        int v = lh[i];
        if (v) atomicAdd(&bcounts[i], v);
    }
}

// ---------------- bucket scan (NB <= 1024, single block) ----------------
__global__ __launch_bounds__(1024) void bscan_kernel(const int* __restrict__ bcounts,
                                                     int* __restrict__ boffs,
                                                     int* __restrict__ bcursor, int NB) {
    __shared__ int wsum[16];
    const int t = threadIdx.x, lane = t & 63, w = t >> 6;
    int x = (t < NB) ? bcounts[t] : 0;
    int s = x;
#pragma unroll
    for (int d = 1; d < 64; d <<= 1) {
        int y = __shfl_up(s, d);
        if (lane >= d) s += y;
    }
    if (lane == 63) wsum[w] = s;
    __syncthreads();
    if (w == 0) {
        int ws = (lane < 16) ? wsum[lane] : 0;
#pragma unroll
        for (int d = 1; d < 16; d <<= 1) {
            int y = __shfl_up(ws, d);
            if (lane >= d) ws += y;
        }
        if (lane < 16) wsum[lane] = ws;
    }
    __syncthreads();
    int excl = (w ? wsum[w - 1] : 0) + s - x;
    if (t < NB) { boffs[t] = excl; bcursor[t] = excl; }
}

// ---------------- partition: per-block bulk reservation, rank in LDS ----------------
__global__ __launch_bounds__(256) void partition_kernel(const int* __restrict__ rows,
                                                        const int* __restrict__ cols,
                                                        const float* __restrict__ vals,
                                                        int* __restrict__ bcursor,
                                                        int2* __restrict__ packed,
                                                        int E, int NB) {
    __shared__ int lh[NBMAX];
    __shared__ int gbase[NBMAX];
    const int t = threadIdx.x;
    const int e0 = blockIdx.x * TILE;

    for (int i = t; i < NB; i += 256) lh[i] = 0;
    __syncthreads();

    int bk[16], rk[16], pc[16], pv[16];
#pragma unroll
    for (int j = 0; j < 16; j++) {
        int idx = e0 + j * 256 + t;
        if (idx < E) {
            int r = rows[idx];
            bk[j] = r >> BSH;
            rk[j] = atomicAdd(&lh[bk[j]], 1);
            pc[j] = ((r & (RPB - 1)) << 17) | cols[idx];
            pv[j] = __float_as_int(vals[idx]);
        } else {
            bk[j] = -1;
        }
    }
    __syncthreads();

    for (int i = t; i < NB; i += 256) {
        int c = lh[i];
        gbase[i] = c ? atomicAdd(&bcursor[i], c) : 0;
    }
    __syncthreads();

#pragma unroll
    for (int j = 0; j < 16; j++) {
        if (bk[j] >= 0) {
            int2 p; p.x = pc[j]; p.y = pv[j];
            packed[(size_t)gbase[bk[j]] + rk[j]] = p;
        }
    }
}

// ------- per-bucket counting sort by (localrow, coltile) -> CSR (+offs/counts) -------
__global__ __launch_bounds__(256) void bucket_scatter(const int2* __restrict__ packed,
                                                      const int* __restrict__ boffs,
                                                      const int* __restrict__ bcounts,
                                                      int* __restrict__ offs,
                                                      int* __restrict__ counts,
                                                      int2* __restrict__ cv, int N) {
    __shared__ int cnt[NKEY];          // 32 KB: counters -> excl prefix -> cursor
    __shared__ int wsum[4];
    const int b = blockIdx.x, t = threadIdx.x;
    const int base = boffs[b], nb = bcounts[b];
    const int lane = t & 63, w = t >> 6;

    for (int i = t; i < NKEY; i += 256) cnt[i] = 0;
    __syncthreads();
    for (int i = t; i < nb; i += 256) {
        int px = packed[base + i].x;
        int key = ((((unsigned)px) >> 17) << 5) | ((px & 0x1FFFF) >> CTSH);
        atomicAdd(&cnt[key], 1);
    }
    __syncthreads();

    // in-place exclusive scan over NKEY counters (32/thread)
    const int K = NKEY / 256;          // 32
    int tsum = 0;
#pragma unroll
    for (int k = 0; k < K; k++) tsum += cnt[t * K + k];
    int ss = tsum;
#pragma unroll
    for (int d = 1; d < 64; d <<= 1) {
        int y = __shfl_up(ss, d);
        if (lane >= d) ss += y;
    }
    if (lane == 63) wsum[w] = ss;
    __syncthreads();
    int wex = 0;
    if (w > 0) wex += wsum[0];
    if (w > 1) wex += wsum[1];
    if (w > 2) wex += wsum[2];
    int run = wex + ss - tsum;         // exclusive prefix of this thread's chunk
    __syncthreads();                   // all reads of cnt done before overwrite
#pragma unroll
    for (int k = 0; k < K; k++) {
        int c = cnt[t * K + k];
        cnt[t * K + k] = run;
        run += c;
    }
    __syncthreads();

    // emit CSR offs/counts (row group = 32 consecutive keys)
    const int r0 = b << BSH;
    for (int lr = t; lr < RPB; lr += 256) {
        int r = r0 + lr;
        if (r < N) {
            int s0 = cnt[lr << 5];
            int s1 = (lr == RPB - 1) ? nb : cnt[(lr + 1) << 5];
            offs[r] = base + s0;
            counts[r] = s1 - s0;
        }
    }
    __syncthreads();

    // scatter using cnt as cursor
    for (int i = t; i < nb; i += 256) {
        int2 p = packed[base + i];
        int key = ((((unsigned)p.x) >> 17) << 5) | ((p.x & 0x1FFFF) >> CTSH);
        int pos = base + atomicAdd(&cnt[key], 1);
        int2 o;
        o.x = p.x & 0x1FFFF;
        o.y = p.y;
        cv[pos] = o;
    }
}

// ------- SpMM: wave per row, col-sorted edges, 8-wide unrolled gathers -------
__global__ __launch_bounds__(256) void spmm_kernel(const unsigned short* __restrict__ S,
                                                   const int* __restrict__ offs,
                                                   const int* __restrict__ counts,
                                                   const int2* __restrict__ cv,
                                                   const float* __restrict__ bias,
                                                   float* __restrict__ out, int N) {
    const int lane = threadIdx.x & 63;
    const int r = blockIdx.x * 4 + (threadIdx.x >> 6);
    if (r >= N) return;
    const char* Sb = reinterpret_cast<const char*>(S);

    float4 acc = { 0.f, 0.f, 0.f, 0.f };
    int i = offs[r];
    const int end = i + counts[r];

#define GATHER(c, v)                                                              \
    {                                                                             \
        uint2 sv = *reinterpret_cast<const uint2*>(Sb + ((size_t)(c) << 9) + (lane << 3)); \
        acc.x += (v) * as_f(sv.x << 16);                                          \
        acc.y += (v) * as_f(sv.x & 0xffff0000u);                                  \
        acc.z += (v) * as_f(sv.y << 16);                                          \
        acc.w += (v) * as_f(sv.y & 0xffff0000u);                                  \
    }

    for (; i + 7 < end; i += 8) {
        int2 e0 = cv[i],     e1 = cv[i + 1], e2 = cv[i + 2], e3 = cv[i + 3];
        int2 e4 = cv[i + 4], e5 = cv[i + 5], e6 = cv[i + 6], e7 = cv[i + 7];
        GATHER(e0.x, as_f((unsigned)e0.y));
        GATHER(e1.x, as_f((unsigned)e1.y));
        GATHER(e2.x, as_f((unsigned)e2.y));
        GATHER(e3.x, as_f((unsigned)e3.y));
        GATHER(e4.x, as_f((unsigned)e4.y));
        GATHER(e5.x, as_f((unsigned)e5.y));
        GATHER(e6.x, as_f((unsigned)e6.y));
        GATHER(e7.x, as_f((unsigned)e7.y));
    }
    for (; i + 1 < end; i += 2) {
        int2 e0 = cv[i], e1 = cv[i + 1];
        GATHER(e0.x, as_f((unsigned)e0.y));
        GATHER(e1.x, as_f((unsigned)e1.y));
    }
    if (i < end) {
        int2 e0 = cv[i];
        GATHER(e0.x, as_f((unsigned)e0.y));
    }
#undef GATHER

    float4 b = reinterpret_cast<const float4*>(bias)[lane];
    float4 o = { acc.x + b.x, acc.y + b.y, acc.z + b.z, acc.w + b.w };
    reinterpret_cast<float4*>(out)[(size_t)r * 64 + lane] = o;
}

extern "C" void kernel_launch(void* const* d_in, const int* in_sizes, int n_in,
                              void* d_out, int out_size, void* d_ws, size_t ws_size,
                              hipStream_t stream) {
    const float* X     = (const float*)d_in[0];
    const float* W     = (const float*)d_in[1];
    const float* bias  = (const float*)d_in[2];
    const float* evals = (const float*)d_in[3];
    const int*   erow  = (const int*)d_in[4];
    const int*   ecol  = (const int*)d_in[5];
    float* out = (float*)d_out;

    const int N = in_sizes[0] / D;
    const int E = in_sizes[3];
    const int NB = (N + RPB - 1) >> BSH;

    char* ws = (char*)d_ws;
    size_t off = 0;
    auto alloc = [&](size_t bytes) {
        void* p = ws + off;
        off += (bytes + 255) & ~(size_t)255;
        return p;
    };
    unsigned short* S  = (unsigned short*)alloc((size_t)N * D * sizeof(unsigned short));
    unsigned short* Wt = (unsigned short*)alloc((size_t)D * D * sizeof(unsigned short));
    int* bcounts = (int*)alloc((size_t)NB * sizeof(int));
    int* boffs   = (int*)alloc((size_t)NB * sizeof(int));
    int* bcursor = (int*)alloc((size_t)NB * sizeof(int));
    int* offs    = (int*)alloc((size_t)N * sizeof(int));
    int* counts  = (int*)alloc((size_t)N * sizeof(int));
    int2* packed = (int2*)alloc((size_t)E * sizeof(int2));
    int2* cv     = (int2*)alloc((size_t)E * sizeof(int2));

    // 1. Wt = bf16(W^T)
    wt_kernel<<<(D * D) / 256, 256, 0, stream>>>(W, Wt);
    // 2. S = bf16(X @ W) via MFMA
    gemm_mfma<<<(N + GBM - 1) / GBM, 1024, 0, stream>>>(X, Wt, S, N);
    // 3. two-phase CSR build, edges sorted by (row, coltile)
    hipMemsetAsync(bcounts, 0, (size_t)NB * sizeof(int), stream);
    bucket_hist<<<1024, 256, 0, stream>>>(erow, bcounts, E, NB);
    bscan_kernel<<<1, 1024, 0, stream>>>(bcounts, boffs, bcursor, NB);
    partition_kernel<<<(E + TILE - 1) / TILE, 256, 0, stream>>>(erow, ecol, evals, bcursor,
                                                                packed, E, NB);
    bucket_scatter<<<NB, 256, 0, stream>>>(packed, boffs, bcounts, offs, counts, cv, N);
    // 4. SpMM + bias (flat loop, 8 gathers in flight)
    spmm_kernel<<<(N + 3) / 4, 256, 0, stream>>>(S, offs, counts, cv, bias, out, N);
}

// Round 7
// 391.049 us; speedup vs baseline: 1.8369x; 1.0359x over previous
//
#include <hip/hip_runtime.h>

#define D 256
#define GBM 256          // gemm rows per block (16 waves x 16)
#define WT_PITCH 264     // bf16 elements per LDS row (256 + 8 pad)
#define BSH 9            // bucket shift: 512 rows per bucket
#define RPB 512          // rows per bucket
#define NBMAX 256        // max buckets (N <= 131072)
#define TILE 4096        // edges per partition block

using bf16x8 = __attribute__((ext_vector_type(8))) short;
using f32x4  = __attribute__((ext_vector_type(4))) float;

static __device__ __forceinline__ unsigned short f2bf(float f) {
    unsigned u = __builtin_bit_cast(unsigned, f);
    return (unsigned short)((u + 0x7fffu + ((u >> 16) & 1u)) >> 16);  // RNE
}
static __device__ __forceinline__ float as_f(unsigned u) {
    return __builtin_bit_cast(float, u);
}

// -------- W transpose + bf16 cast (+ zero bcounts): Wt[n][k] = bf16(W[k][n]) --------
__global__ void wt_kernel(const float* __restrict__ W, unsigned short* __restrict__ Wt,
                          int* __restrict__ bcounts, int NB) {
    int idx = blockIdx.x * blockDim.x + threadIdx.x;
    int n = idx & 255, k = idx >> 8;
    Wt[n * 256 + k] = f2bf(W[k * 256 + n]);
    if (blockIdx.x == 0 && threadIdx.x < NB) bcounts[threadIdx.x] = 0;
}

// ---------------- GEMM: S(bf16) = X @ W via MFMA, full Wt in LDS ----------------
__global__ __launch_bounds__(1024) void gemm_mfma(const float* __restrict__ X,
                                                  const unsigned short* __restrict__ Wt,
                                                  unsigned short* __restrict__ S, int N) {
    __shared__ unsigned short wlds[256 * WT_PITCH];    // 132 KB

    for (int c = threadIdx.x; c < 8192; c += 1024) {
        int n = c >> 5, kc = c & 31;
        uint4 v = *reinterpret_cast<const uint4*>(Wt + n * 256 + kc * 8);
        *reinterpret_cast<uint4*>(&wlds[n * WT_PITCH + kc * 8]) = v;
    }
    __syncthreads();

    const int lane = threadIdx.x & 63;
    const int wave = threadIdx.x >> 6;
    const int row0 = blockIdx.x * GBM + wave * 16;
    const int l16  = lane & 15;
    const int kgrp = lane >> 4;
    const int arow = min(row0 + l16, N - 1);
    const float* xp = X + (size_t)arow * 256 + kgrp * 8;

    f32x4 acc[16];
#pragma unroll
    for (int i = 0; i < 16; i++) acc[i] = (f32x4)(0.0f);

#pragma unroll
    for (int ks = 0; ks < 8; ks++) {
        float4 a0 = *reinterpret_cast<const float4*>(xp + ks * 32);
        float4 a1 = *reinterpret_cast<const float4*>(xp + ks * 32 + 4);
        bf16x8 af;
        af[0] = (short)f2bf(a0.x); af[1] = (short)f2bf(a0.y);
        af[2] = (short)f2bf(a0.z); af[3] = (short)f2bf(a0.w);
        af[4] = (short)f2bf(a1.x); af[5] = (short)f2bf(a1.y);
        af[6] = (short)f2bf(a1.z); af[7] = (short)f2bf(a1.w);
#pragma unroll
        for (int nt = 0; nt < 16; nt++) {
            bf16x8 bf = *reinterpret_cast<const bf16x8*>(
                &wlds[(nt * 16 + l16) * WT_PITCH + ks * 32 + kgrp * 8]);
            acc[nt] = __builtin_amdgcn_mfma_f32_16x16x32_bf16(af, bf, acc[nt], 0, 0, 0);
        }
    }

#pragma unroll
    for (int nt = 0; nt < 16; nt++) {
#pragma unroll
        for (int j = 0; j < 4; j++) {
            int r = row0 + kgrp * 4 + j;
            if (r < N) S[(size_t)r * 256 + nt * 16 + l16] = f2bf(acc[nt][j]);
        }
    }
}

// ---------------- bucket histogram (LDS-aggregated) ----------------
__global__ __launch_bounds__(256) void bucket_hist(const int* __restrict__ rows,
                                                   int* __restrict__ bcounts,
                                                   int E, int NB) {
    __shared__ int lh[NBMAX];
    for (int i = threadIdx.x; i < NB; i += 256) lh[i] = 0;
    __syncthreads();
    const int stride = gridDim.x * 256;
    for (int e = blockIdx.x * 256 + threadIdx.x; e < E; e += stride)
        atomicAdd(&lh[rows[e] >> BSH], 1);
    __syncthreads();
    for (int i = threadIdx.x; i < NB; i += 256) {
        int v = lh[i];
        if (v) atomicAdd(&bcounts[i], v);
    }
}

// ---------------- bucket scan (NB <= 1024, single block) ----------------
__global__ __launch_bounds__(1024) void bscan_kernel(const int* __restrict__ bcounts,
                                                     int* __restrict__ boffs,
                                                     int* __restrict__ bcursor, int NB) {
    __shared__ int wsum[16];
    const int t = threadIdx.x, lane = t & 63, w = t >> 6;
    int x = (t < NB) ? bcounts[t] : 0;
    int s = x;
#pragma unroll
    for (int d = 1; d < 64; d <<= 1) {
        int y = __shfl_up(s, d);
        if (lane >= d) s += y;
    }
    if (lane == 63) wsum[w] = s;
    __syncthreads();
    if (w == 0) {
        int ws = (lane < 16) ? wsum[lane] : 0;
#pragma unroll
        for (int d = 1; d < 16; d <<= 1) {
            int y = __shfl_up(ws, d);
            if (lane >= d) ws += y;
        }
        if (lane < 16) wsum[lane] = ws;
    }
    __syncthreads();
    int excl = (w ? wsum[w - 1] : 0) + s - x;
    if (t < NB) { boffs[t] = excl; bcursor[t] = excl; }
}

// ---------------- partition: per-block bulk reservation, rank in LDS ----------------
__global__ __launch_bounds__(256) void partition_kernel(const int* __restrict__ rows,
                                                        const int* __restrict__ cols,
                                                        const float* __restrict__ vals,
                                                        int* __restrict__ bcursor,
                                                        int2* __restrict__ packed,
                                                        int E, int NB) {
    __shared__ int lh[NBMAX];
    __shared__ int gbase[NBMAX];
    const int t = threadIdx.x;
    const int e0 = blockIdx.x * TILE;

    for (int i = t; i < NB; i += 256) lh[i] = 0;
    __syncthreads();

    int bk[16], rk[16], pc[16], pv[16];
#pragma unroll
    for (int j = 0; j < 16; j++) {
        int idx = e0 + j * 256 + t;
        if (idx < E) {
            int r = rows[idx];
            bk[j] = r >> BSH;
            rk[j] = atomicAdd(&lh[bk[j]], 1);
            pc[j] = ((r & (RPB - 1)) << 17) | cols[idx];
            pv[j] = __float_as_int(vals[idx]);
        } else {
            bk[j] = -1;
        }
    }
    __syncthreads();

    for (int i = t; i < NB; i += 256) {
        int c = lh[i];
        gbase[i] = c ? atomicAdd(&bcursor[i], c) : 0;
    }
    __syncthreads();

#pragma unroll
    for (int j = 0; j < 16; j++) {
        if (bk[j] >= 0) {
            int2 p; p.x = pc[j]; p.y = pv[j];
            packed[(size_t)gbase[bk[j]] + rk[j]] = p;
        }
    }
}

// ------- per-bucket counting sort by localrow -> CSR (+offs/counts) -------
__global__ __launch_bounds__(256) void bucket_scatter(const int2* __restrict__ packed,
                                                      const int* __restrict__ boffs,
                                                      const int* __restrict__ bcounts,
                                                      int* __restrict__ offs,
                                                      int* __restrict__ counts,
                                                      int2* __restrict__ cv, int N) {
    __shared__ int cnt[RPB];
    __shared__ int lofs[RPB];
    __shared__ int wsum[4];
    const int b = blockIdx.x, t = threadIdx.x;
    const int base = boffs[b], nb = bcounts[b];
    const int lane = t & 63, w = t >> 6;

    for (int i = t; i < RPB; i += 256) cnt[i] = 0;
    __syncthreads();
    for (int i = t; i < nb; i += 256)
        atomicAdd(&cnt[((unsigned)packed[base + i].x) >> 17], 1);
    __syncthreads();

    // exclusive scan over 512 counters: 2 per thread + wave scan
    int a0 = cnt[2 * t], a1 = cnt[2 * t + 1];
    int s = a0 + a1;
    int ss = s;
#pragma unroll
    for (int d = 1; d < 64; d <<= 1) {
        int y = __shfl_up(ss, d);
        if (lane >= d) ss += y;
    }
    if (lane == 63) wsum[w] = ss;
    __syncthreads();
    int wex = 0;
    if (w > 0) wex += wsum[0];
    if (w > 1) wex += wsum[1];
    if (w > 2) wex += wsum[2];
    int excl = wex + ss - s;

    const int r0 = b << BSH;
    int r = r0 + 2 * t;
    if (r < N)     { offs[r]     = base + excl;      counts[r]     = a0; }
    if (r + 1 < N) { offs[r + 1] = base + excl + a0; counts[r + 1] = a1; }
    lofs[2 * t]     = excl;
    lofs[2 * t + 1] = excl + a0;
    __syncthreads();

    for (int i = t; i < nb; i += 256) {
        int2 p = packed[base + i];
        int lr = ((unsigned)p.x) >> 17;
        int pos = base + atomicAdd(&lofs[lr], 1);
        int2 o;
        o.x = p.x & 0x1FFFF;
        o.y = p.y;
        cv[pos] = o;
    }
}

// ------- SpMM: wave per row, PAIRED-edge dwordx4 gathers (2 edges / instr) -------
__global__ __launch_bounds__(256) void spmm_kernel(const unsigned short* __restrict__ S,
                                                   const int* __restrict__ offs,
                                                   const int* __restrict__ counts,
                                                   const int2* __restrict__ cv,
                                                   const float* __restrict__ bias,
                                                   float* __restrict__ out, int N) {
    const int lane = threadIdx.x & 63;
    const int half = lane >> 5;          // 0: edge A of pair, 1: edge B
    const int l32  = lane & 31;          // covers cols l32*8 .. l32*8+7 (16 B of S row)
    const int r = blockIdx.x * 4 + (threadIdx.x >> 6);
    if (r >= N) return;
    const char* Sb = reinterpret_cast<const char*>(S);

    float acc[8] = {0.f, 0.f, 0.f, 0.f, 0.f, 0.f, 0.f, 0.f};
    int i = offs[r];
    const int end = i + counts[r];

#define GPAIR(c0, v0, c1, v1)                                                     \
    {                                                                             \
        int   c = half ? (c1) : (c0);                                             \
        float v = half ? (v1) : (v0);                                             \
        uint4 sv = *reinterpret_cast<const uint4*>(Sb + ((size_t)c << 9) + (l32 << 4)); \
        acc[0] += v * as_f(sv.x << 16);                                           \
        acc[1] += v * as_f(sv.x & 0xffff0000u);                                   \
        acc[2] += v * as_f(sv.y << 16);                                           \
        acc[3] += v * as_f(sv.y & 0xffff0000u);                                   \
        acc[4] += v * as_f(sv.z << 16);                                           \
        acc[5] += v * as_f(sv.z & 0xffff0000u);                                   \
        acc[6] += v * as_f(sv.w << 16);                                           \
        acc[7] += v * as_f(sv.w & 0xffff0000u);                                   \
    }

    // 4 pairs (8 edges) per iteration: 4 independent dwordx4 gathers in flight
    for (; i + 7 < end; i += 8) {
        int2 e0 = cv[i],     e1 = cv[i + 1], e2 = cv[i + 2], e3 = cv[i + 3];
        int2 e4 = cv[i + 4], e5 = cv[i + 5], e6 = cv[i + 6], e7 = cv[i + 7];
        GPAIR(e0.x, as_f((unsigned)e0.y), e1.x, as_f((unsigned)e1.y));
        GPAIR(e2.x, as_f((unsigned)e2.y), e3.x, as_f((unsigned)e3.y));
        GPAIR(e4.x, as_f((unsigned)e4.y), e5.x, as_f((unsigned)e5.y));
        GPAIR(e6.x, as_f((unsigned)e6.y), e7.x, as_f((unsigned)e7.y));
    }
    for (; i + 1 < end; i += 2) {
        int2 e0 = cv[i], e1 = cv[i + 1];
        GPAIR(e0.x, as_f((unsigned)e0.y), e1.x, as_f((unsigned)e1.y));
    }
    if (i < end) {
        int2 e0 = cv[i];
        GPAIR(e0.x, as_f((unsigned)e0.y), e0.x, 0.0f);
    }
#undef GPAIR

    // cross-half reduce: both halves accumulated different edges of same row
#pragma unroll
    for (int j = 0; j < 8; j++) acc[j] += __shfl_xor(acc[j], 32);

    // lane writes one float4: cols l32*8 + half*4 .. +3
    float4 bv = reinterpret_cast<const float4*>(bias)[l32 * 2 + half];
    float4 o = { acc[half * 4 + 0] + bv.x, acc[half * 4 + 1] + bv.y,
                 acc[half * 4 + 2] + bv.z, acc[half * 4 + 3] + bv.w };
    reinterpret_cast<float4*>(out)[(size_t)r * 64 + l32 * 2 + half] = o;
}

extern "C" void kernel_launch(void* const* d_in, const int* in_sizes, int n_in,
                              void* d_out, int out_size, void* d_ws, size_t ws_size,
                              hipStream_t stream) {
    const float* X     = (const float*)d_in[0];
    const float* W     = (const float*)d_in[1];
    const float* bias  = (const float*)d_in[2];
    const float* evals = (const float*)d_in[3];
    const int*   erow  = (const int*)d_in[4];
    const int*   ecol  = (const int*)d_in[5];
    float* out = (float*)d_out;

    const int N = in_sizes[0] / D;
    const int E = in_sizes[3];
    const int NB = ((N + RPB - 1) >> BSH);

    char* ws = (char*)d_ws;
    size_t off = 0;
    auto alloc = [&](size_t bytes) {
        void* p = ws + off;
        off += (bytes + 255) & ~(size_t)255;
        return p;
    };
    unsigned short* S  = (unsigned short*)alloc((size_t)N * D * sizeof(unsigned short));
    unsigned short* Wt = (unsigned short*)alloc((size_t)D * D * sizeof(unsigned short));
    int* bcounts = (int*)alloc((size_t)NB * sizeof(int));
    int* boffs   = (int*)alloc((size_t)NB * sizeof(int));
    int* bcursor = (int*)alloc((size_t)NB * sizeof(int));
    int* offs    = (int*)alloc((size_t)N * sizeof(int));
    int* counts  = (int*)alloc((size_t)N * sizeof(int));
    int2* packed = (int2*)alloc((size_t)E * sizeof(int2));
    int2* cv     = (int2*)alloc((size_t)E * sizeof(int2));

    // 1. Wt = bf16(W^T), zero bcounts
    wt_kernel<<<(D * D) / 256, 256, 0, stream>>>(W, Wt, bcounts, NB);
    // 2. S = bf16(X @ W) via MFMA
    gemm_mfma<<<(N + GBM - 1) / GBM, 1024, 0, stream>>>(X, Wt, S, N);
    // 3. two-phase CSR build
    bucket_hist<<<1024, 256, 0, stream>>>(erow, bcounts, E, NB);
    bscan_kernel<<<1, 1024, 0, stream>>>(bcounts, boffs, bcursor, NB);
    partition_kernel<<<(E + TILE - 1) / TILE, 256, 0, stream>>>(erow, ecol, evals, bcursor,
                                                                packed, E, NB);
    bucket_scatter<<<NB, 256, 0, stream>>>(packed, boffs, bcounts, offs, counts, cv, N);
    // 4. SpMM + bias (paired-edge gathers)
    spmm_kernel<<<(N + 3) / 4, 256, 0, stream>>>(S, offs, counts, cv, bias, out, N);
}